// Round 4
// baseline (118.969 us; speedup 1.0000x reference)
//
#include <hip/hip_runtime.h>
#include <hip/hip_fp16.h>

typedef __attribute__((ext_vector_type(2))) float v2f;

#define B_ 16
#define NPTS 4096            // points per batch (N == M == 4096)

constexpr int BLK    = 128;            // threads per block (2 waves)
constexpr int PPT    = 16;             // query points per thread (8 packed pairs)
constexpr int NP     = PPT / 2;        // packed pairs per thread
constexpr int CHUNK  = BLK * PPT;      // 2048 query points per block
constexpr int NCHUNK = NPTS / CHUNK;   // 2
constexpr int JT     = 256;            // target-tile size (LDS: 4 KB of float4)
constexpr int NJT    = NPTS / JT;      // 16

// ------------------------------------------------------------------
// main pass: block = (query chunk cx, target tile jt, batch b, dir).
// LDS holds JT prescaled targets {-2x,-2y,-2z,|g|^2}. Queries live in
// registers as float2 packs so the dot chain runs on v_pk_fma_f32
// (packed fp32 = 2x scalar rate); two targets merge into the running
// min via v_min3_f32. 2 VALU inst/pair; 1 broadcast ds_read_b128 per
// 16 query-pairs. Tile-min of clamped d^2 stored as half (4 MB total).
__global__ __launch_bounds__(BLK, 2) void chamfer_pass(
        const float* __restrict__ pred, const float* __restrict__ gt,
        __half* __restrict__ partial) {
    const int cx  = blockIdx.x & (NCHUNK - 1);   // query chunk
    const int jt  = blockIdx.x >> 1;             // target tile
    const int b   = blockIdx.y;
    const int dir = blockIdx.z;

    const float* qsrc = dir ? gt   : pred;       // queries
    const float* tsrc = dir ? pred : gt;         // targets

    __shared__ float4 sh[JT];
    {
        const float* tp = tsrc + (b * NPTS + jt * JT) * 3;
        for (int k = threadIdx.x; k < JT; k += BLK) {
            float x = tp[k * 3 + 0];
            float y = tp[k * 3 + 1];
            float z = tp[k * 3 + 2];
            sh[k] = make_float4(-2.0f * x, -2.0f * y, -2.0f * z,
                                fmaf(x, x, fmaf(y, y, z * z)));
        }
    }

    v2f px[NP], py[NP], pz[NP], mn[NP];
    const int qbase = b * NPTS + cx * CHUNK + threadIdx.x;
#pragma unroll
    for (int p = 0; p < NP; p++) {
        int i0 = (qbase + (2 * p)     * BLK) * 3;
        int i1 = (qbase + (2 * p + 1) * BLK) * 3;
        px[p].x = qsrc[i0 + 0];  px[p].y = qsrc[i1 + 0];
        py[p].x = qsrc[i0 + 1];  py[p].y = qsrc[i1 + 1];
        pz[p].x = qsrc[i0 + 2];  pz[p].y = qsrc[i1 + 2];
        mn[p].x = 1e30f;         mn[p].y = 1e30f;
    }
    __syncthreads();

#pragma unroll 2
    for (int j = 0; j < JT; j += 2) {
        float4 g0 = sh[j];       // uniform addr -> broadcast ds_read_b128
        float4 g1 = sh[j + 1];
        v2f g0x = {g0.x, g0.x}, g0y = {g0.y, g0.y}, g0z = {g0.z, g0.z}, g0w = {g0.w, g0.w};
        v2f g1x = {g1.x, g1.x}, g1y = {g1.y, g1.y}, g1z = {g1.z, g1.z}, g1w = {g1.w, g1.w};
#pragma unroll
        for (int p = 0; p < NP; p++) {
            v2f t0 = __builtin_elementwise_fma(g0x, px[p], g0w);
            t0     = __builtin_elementwise_fma(g0y, py[p], t0);
            t0     = __builtin_elementwise_fma(g0z, pz[p], t0);
            v2f t1 = __builtin_elementwise_fma(g1x, px[p], g1w);
            t1     = __builtin_elementwise_fma(g1y, py[p], t1);
            t1     = __builtin_elementwise_fma(g1z, pz[p], t1);
            mn[p].x = fminf(mn[p].x, fminf(t0.x, t1.x));   // -> v_min3_f32
            mn[p].y = fminf(mn[p].y, fminf(t0.y, t1.y));
        }
    }

    // partial[dir][b][jt][point] = clamped min d^2 over this tile (half)
    __half* slot = partial + ((dir * B_ + b) * NJT + jt) * NPTS
                 + cx * CHUNK + threadIdx.x;
#pragma unroll
    for (int p = 0; p < NP; p++) {
        v2f x2 = __builtin_elementwise_fma(pz[p], pz[p],
                 __builtin_elementwise_fma(py[p], py[p], px[p] * px[p]));
        slot[(2 * p)     * BLK] = __float2half(fmaxf(mn[p].x + x2.x, 0.0f));
        slot[(2 * p + 1) * BLK] = __float2half(fmaxf(mn[p].y + x2.y, 0.0f));
    }
}

// ------------------------------------------------------------------
// fused reduce: 512 blocks; block = (dir*B+b, 256-point segment).
// Min over NJT tile slots, sqrt, block-sum, then atomicAdd the scaled
// contribution straight into the (pre-zeroed) 3-float output.
__global__ void reduce_kernel(const __half* __restrict__ partial,
                              float* __restrict__ out) {
    const int slot = blockIdx.x >> 4;    // (dir*B + b) in [0,32)
    const int seg  = blockIdx.x & 15;    // point segment
    const __half* p = partial + slot * (NJT * NPTS) + seg * 256 + threadIdx.x;
    float v = __half2float(p[0]);
#pragma unroll
    for (int jt = 1; jt < NJT; jt++)
        v = fminf(v, __half2float(p[jt * NPTS]));
    float s = sqrtf(v);
    for (int off = 32; off; off >>= 1) s += __shfl_down(s, off);
    __shared__ float ps[4];
    if ((threadIdx.x & 63) == 0) ps[threadIdx.x >> 6] = s;
    __syncthreads();
    if (threadIdx.x == 0) {
        float t = (ps[0] + ps[1] + ps[2] + ps[3]) * (1.0f / (float)(B_ * NPTS));
        atomicAdd(&out[0], t);          // WEIGHT * loss, WEIGHT = 1
        atomicAdd(&out[1], t);          // helper_loss
        atomicAdd(&out[2], 0.1f * t);   // helper_cderr = p1 chamfer * xyz_unit
    }
}

// ------------------------------------------------------------------
extern "C" void kernel_launch(void* const* d_in, const int* in_sizes, int n_in,
                              void* d_out, int out_size, void* d_ws, size_t ws_size,
                              hipStream_t stream) {
    const float* pred = (const float*)d_in[0];
    const float* gt   = (const float*)d_in[1];
    float* out = (float*)d_out;

    __half* partial = (__half*)d_ws;   // 2*B*NJT*NPTS halves = 4 MB

    hipMemsetAsync(d_out, 0, 3 * sizeof(float), stream);
    chamfer_pass<<<dim3(NCHUNK * NJT, B_, 2), BLK, 0, stream>>>(pred, gt, partial);
    reduce_kernel<<<dim3(512), 256, 0, stream>>>(partial, out);
}

// Round 5
// 101.575 us; speedup vs baseline: 1.1712x; 1.1712x over previous
//
#include <hip/hip_runtime.h>

typedef __attribute__((ext_vector_type(2))) float v2f;

#define B_ 16
#define NPTS 4096            // points per batch (N == M == 4096)

constexpr int BLK   = 1024;          // 16 waves per block
constexpr int WV    = 16;            // waves per block
constexpr int PPT   = 8;             // query points per thread
constexpr int NP    = PPT / 2;       // packed pairs per thread
constexpr int CHUNK = 64 * PPT;      // 512 queries per block (shared by all waves)
constexpr int NCH   = NPTS / CHUNK;  // 8 query chunks per (dir, batch)
constexpr int TILE  = 2048;          // targets staged per LDS tile (32 KB)
constexpr int NT    = NPTS / TILE;   // 2 tiles
constexpr int SEG   = TILE / WV;     // 128 targets per wave per tile
constexpr int NBLK  = 2 * B_ * NCH;  // 256 blocks total

// ------------------------------------------------------------------
// Fully fused chamfer: block = (dir, batch, 512-query chunk) covering
// ALL 4096 targets. 16 waves share the block's queries and split the
// targets 16 ways; per-wave mins (with |q|^2 folded in and clamped)
// meet in LDS, the block sums sqrt() over its queries and does ONE
// atomicAdd into a ws accumulator; the last block writes the 3 outputs.
__global__ __launch_bounds__(BLK) void chamfer_fused(
        const float* __restrict__ pred, const float* __restrict__ gt,
        float* __restrict__ accum, unsigned* __restrict__ counter,
        float* __restrict__ out) {
    const int dir = blockIdx.x >> 7;          // 0..1
    const int b   = (blockIdx.x >> 3) & 15;   // batch
    const int cx  = blockIdx.x & 7;           // query chunk

    const float* qsrc = dir ? gt   : pred;    // queries
    const float* tsrc = dir ? pred : gt;      // targets

    __shared__ float4 sh[TILE];               // 32 KB prescaled targets
    __shared__ float  comb[WV][CHUNK];        // 32 KB cross-wave combine
    __shared__ float  ps[8];

    const int lane = threadIdx.x & 63;
    const int wv   = threadIdx.x >> 6;

    // Load the block's 512 queries (every wave holds the same ones).
    v2f px[NP], py[NP], pz[NP], mn[NP];
    const float* qp = qsrc + (b * NPTS + cx * CHUNK) * 3;
#pragma unroll
    for (int p = 0; p < NP; p++) {
        int i0 = (lane + (2 * p)     * 64) * 3;
        int i1 = (lane + (2 * p + 1) * 64) * 3;
        px[p] = v2f{qp[i0 + 0], qp[i1 + 0]};
        py[p] = v2f{qp[i0 + 1], qp[i1 + 1]};
        pz[p] = v2f{qp[i0 + 2], qp[i1 + 2]};
        mn[p] = v2f{1e30f, 1e30f};
    }

    for (int t = 0; t < NT; t++) {
        if (t) __syncthreads();               // protect sh[] reuse
        // stage TILE targets as {-2x,-2y,-2z,|g|^2}
        const float* tp = tsrc + (b * NPTS + t * TILE) * 3;
        for (int k = threadIdx.x; k < TILE; k += BLK) {
            float x = tp[3 * k + 0];
            float y = tp[3 * k + 1];
            float z = tp[3 * k + 2];
            sh[k] = make_float4(-2.0f * x, -2.0f * y, -2.0f * z,
                                fmaf(x, x, fmaf(y, y, z * z)));
        }
        __syncthreads();

        // each wave sweeps its private 128-target segment (broadcast reads)
        const float4* seg = &sh[wv * SEG];
#pragma unroll 4
        for (int j = 0; j < SEG; j += 2) {
            float4 g0 = seg[j];
            float4 g1 = seg[j + 1];
            v2f g0x = {g0.x, g0.x}, g0y = {g0.y, g0.y}, g0z = {g0.z, g0.z}, g0w = {g0.w, g0.w};
            v2f g1x = {g1.x, g1.x}, g1y = {g1.y, g1.y}, g1z = {g1.z, g1.z}, g1w = {g1.w, g1.w};
#pragma unroll
            for (int p = 0; p < NP; p++) {
                v2f t0 = __builtin_elementwise_fma(g0x, px[p], g0w);
                t0     = __builtin_elementwise_fma(g0y, py[p], t0);
                t0     = __builtin_elementwise_fma(g0z, pz[p], t0);
                v2f t1 = __builtin_elementwise_fma(g1x, px[p], g1w);
                t1     = __builtin_elementwise_fma(g1y, py[p], t1);
                t1     = __builtin_elementwise_fma(g1z, pz[p], t1);
                mn[p].x = fminf(mn[p].x, fminf(t0.x, t1.x));   // -> v_min3_f32
                mn[p].y = fminf(mn[p].y, fminf(t0.y, t1.y));
            }
        }
    }

    // fold |q|^2, clamp, publish per-wave partial mins
#pragma unroll
    for (int p = 0; p < NP; p++) {
        v2f x2 = __builtin_elementwise_fma(pz[p], pz[p],
                 __builtin_elementwise_fma(py[p], py[p], px[p] * px[p]));
        comb[wv][lane + (2 * p)     * 64] = fmaxf(mn[p].x + x2.x, 0.0f);
        comb[wv][lane + (2 * p + 1) * 64] = fmaxf(mn[p].y + x2.y, 0.0f);
    }
    __syncthreads();

    // cross-wave min + sqrt: thread t (< 512) owns query t
    float s = 0.0f;
    if (threadIdx.x < CHUNK) {
        float v = comb[0][threadIdx.x];
#pragma unroll
        for (int w = 1; w < WV; w++)
            v = fminf(v, comb[w][threadIdx.x]);
        s = sqrtf(v);
    }
    for (int off = 32; off; off >>= 1) s += __shfl_down(s, off);
    if (lane == 0 && wv < 8) ps[wv] = s;
    __syncthreads();

    if (threadIdx.x == 0) {
        float sb = ps[0] + ps[1] + ps[2] + ps[3] + ps[4] + ps[5] + ps[6] + ps[7];
        atomicAdd(accum, sb);
        __threadfence();
        unsigned old = atomicAdd(counter, 1u);
        if (old == NBLK - 1) {               // last block finalizes
            float total = atomicAdd(accum, 0.0f);   // coherent read
            float loss  = total * (1.0f / (float)(B_ * NPTS));
            out[0] = loss;          // WEIGHT * loss, WEIGHT = 1
            out[1] = loss;          // helper_loss
            out[2] = 0.1f * loss;   // helper_cderr = p1 chamfer * xyz_unit
        }
    }
}

// ------------------------------------------------------------------
extern "C" void kernel_launch(void* const* d_in, const int* in_sizes, int n_in,
                              void* d_out, int out_size, void* d_ws, size_t ws_size,
                              hipStream_t stream) {
    const float* pred = (const float*)d_in[0];
    const float* gt   = (const float*)d_in[1];
    float*    out     = (float*)d_out;
    float*    accum   = (float*)d_ws;
    unsigned* counter = (unsigned*)d_ws + 1;

    hipMemsetAsync(d_ws, 0, 2 * sizeof(float), stream);
    chamfer_fused<<<dim3(NBLK), BLK, 0, stream>>>(pred, gt, accum, counter, out);
}